// Round 1
// baseline (1354.638 us; speedup 1.0000x reference)
//
#include <hip/hip_runtime.h>
#include <hip/hip_bf16.h>

typedef __bf16 bf16x4_v __attribute__((ext_vector_type(4)));
typedef __bf16 bf16x8_v __attribute__((ext_vector_type(8)));
typedef float  f32x4_v  __attribute__((ext_vector_type(4)));

static constexpr int kH = 1024;
static constexpr int kD = 2048;   // 2H
static constexpr int kB = 64;
static constexpr int kS = 2048;
static constexpr int kM = kB * kS;  // 131072 rows of the big GEMM

__device__ __forceinline__ void load_lds16(const void* g, void* l) {
  __builtin_amdgcn_global_load_lds(
      (const __attribute__((address_space(1))) unsigned int*)g,
      (__attribute__((address_space(3))) unsigned int*)l, 16, 0, 0);
}

__device__ __forceinline__ float fast_tanh(float x) {
  // tanh(x) = 1 - 2/(exp(2x)+1); v_exp + v_rcp, saturates correctly at +-inf
  float e = __expf(2.0f * x);
  return 1.0f - 2.0f * __builtin_amdgcn_rcpf(e + 1.0f);
}

// ---------------- W_h fp32 -> bf16 (8 MB -> 4 MB, once per launch) ----------
__global__ __launch_bounds__(256) void conv_wh_kernel(const float* __restrict__ W,
                                                      __bf16* __restrict__ out) {
  int i = (blockIdx.x * 256 + threadIdx.x) * 4;
  float4 v = *reinterpret_cast<const float4*>(W + i);
  bf16x4_v o = {(__bf16)v.x, (__bf16)v.y, (__bf16)v.z, (__bf16)v.w};
  *reinterpret_cast<bf16x4_v*>(out + i) = o;
}

// ------------- biasBH[b][h] = s_t[b] . W_s[h] + b_s[h] + b_h[h] -------------
// one wave per output; coalesced reads of the W_s row
__global__ __launch_bounds__(256) void prep_bias_kernel(
    const float* __restrict__ s_t, const float* __restrict__ W_s,
    const float* __restrict__ b_s, const float* __restrict__ b_h,
    float* __restrict__ biasBH) {
  int wave = blockIdx.x * 4 + (threadIdx.x >> 6);  // 65536 outputs
  int lane = threadIdx.x & 63;
  int b = wave >> 10, h = wave & 1023;
  const float4* sp = reinterpret_cast<const float4*>(s_t + (size_t)b * kD);
  const float4* wp = reinterpret_cast<const float4*>(W_s + (size_t)h * kD);
  float acc = 0.f;
  for (int i = lane; i < kD / 4; i += 64) {
    float4 a = sp[i], w = wp[i];
    acc += a.x * w.x + a.y * w.y + a.z * w.z + a.w * w.w;
  }
  for (int m = 1; m < 64; m <<= 1) acc += __shfl_xor(acc, m);
  if (lane == 0) biasBH[wave] = acc + b_s[h] + b_h[h];
}

// ---------------- big GEMM + fused tanh/v_a epilogue -> E -------------------
// 128x128 tile, 4 waves (2x2), 16x16x32 bf16 MFMA, BK=32.
// A (h_i fp32) is reg-staged with on-the-fly bf16 conversion; B (W_h bf16)
// staged via global_load_lds width-16.
__global__ void gemm_score_kernel(
    const float* __restrict__ h_i,      // (kM, kD) fp32
    const __bf16* __restrict__ Wh,      // (kH, kD) bf16
    const float* __restrict__ biasBH,   // (kB, kH)
    const float* __restrict__ coverage, // (kB, kS)
    const float* __restrict__ Wc,       // (kH)
    const float* __restrict__ va,       // (kH)
    float* __restrict__ E) {            // (kB, kS), pre-zeroed
  const int n0 = blockIdx.x * 128;  // 8 N-chunks (x fastest => L3 sharing of A)
  const int m0 = blockIdx.y * 128;  // 1024 M-tiles
  const int tid = threadIdx.x;
  const int lane = tid & 63;
  const int wid = tid >> 6;        // 0..3
  const int wm = wid >> 1, wn = wid & 1;

  __shared__ __bf16 As[128][32];
  __shared__ __bf16 Bs[128][32];

  f32x4_v acc[4][4];
#pragma unroll
  for (int m = 0; m < 4; ++m)
#pragma unroll
    for (int n = 0; n < 4; ++n) acc[m][n] = {0.f, 0.f, 0.f, 0.f};

  const int kofs = (lane >> 4) * 8;
  const int rA = wm * 64 + (lane & 15);
  const int rB = wn * 64 + (lane & 15);

  for (int k0 = 0; k0 < kD; k0 += 32) {
    // ---- stage B: wave wid covers Bs rows [wid*32, wid*32+32)
    {
      const __bf16* gB = Wh + (size_t)(n0 + wid * 32) * kD + k0;
#pragma unroll
      for (int q = 0; q < 2; ++q) {
        const __bf16* src = gB + (size_t)(q * 16 + (lane >> 2)) * kD + (lane & 3) * 8;
        load_lds16(src, &Bs[wid * 32 + q * 16][0]);
      }
    }
    // ---- stage A: 128x32 fp32 -> bf16, 4 float4 per thread
    {
      const float* Ag = h_i + (size_t)m0 * kD + k0;
#pragma unroll
      for (int j = 0; j < 4; ++j) {
        int idx = j * 256 + tid;   // 0..1023
        int row = idx >> 3;        // 0..127
        int c4 = idx & 7;          // float4 within the 32-wide K slice
        float4 v = *reinterpret_cast<const float4*>(Ag + (size_t)row * kD + c4 * 4);
        bf16x4_v o = {(__bf16)v.x, (__bf16)v.y, (__bf16)v.z, (__bf16)v.w};
        *reinterpret_cast<bf16x4_v*>(&As[row][c4 * 4]) = o;
      }
    }
    __syncthreads();

    bf16x8_v a[4], b[4];
#pragma unroll
    for (int m = 0; m < 4; ++m)
      a[m] = *reinterpret_cast<const bf16x8_v*>(&As[rA + m * 16][kofs]);
#pragma unroll
    for (int n = 0; n < 4; ++n)
      b[n] = *reinterpret_cast<const bf16x8_v*>(&Bs[rB + n * 16][kofs]);
#pragma unroll
    for (int m = 0; m < 4; ++m)
#pragma unroll
      for (int n = 0; n < 4; ++n)
        acc[m][n] = __builtin_amdgcn_mfma_f32_16x16x32_bf16(a[m], b[n], acc[m][n], 0, 0, 0);
    __syncthreads();
  }

  // ---- epilogue: z = acc + bias + cov*Wc; E_partial = sum_h tanh(z)*va[h]
  const int bb = m0 >> 11;            // batch (uniform: 128 | 2048)
  const int colg = lane & 15;
  const int rowg = lane >> 4;         // 0..3
  float bias_v[4], wc_v[4], va_v[4];
#pragma unroll
  for (int n = 0; n < 4; ++n) {
    int h = n0 + wn * 64 + n * 16 + colg;
    bias_v[n] = biasBH[bb * kH + h];
    wc_v[n] = Wc[h];
    va_v[n] = va[h];
  }
  const int s_tile = (m0 & (kS - 1));
  float rowsum[4][4];
#pragma unroll
  for (int m = 0; m < 4; ++m)
#pragma unroll
    for (int j = 0; j < 4; ++j) rowsum[m][j] = 0.f;

#pragma unroll
  for (int m = 0; m < 4; ++m) {
    int sbase = s_tile + wm * 64 + m * 16 + rowg * 4;
    float cov[4];
#pragma unroll
    for (int j = 0; j < 4; ++j) cov[j] = coverage[bb * kS + sbase + j];
#pragma unroll
    for (int n = 0; n < 4; ++n) {
#pragma unroll
      for (int j = 0; j < 4; ++j) {
        float z = acc[m][n][j] + bias_v[n] + cov[j] * wc_v[n];
        rowsum[m][j] += fast_tanh(z) * va_v[n];
      }
    }
  }
  // reduce across the 16 column-lanes, then one atomicAdd per row per wave
#pragma unroll
  for (int m = 0; m < 4; ++m) {
#pragma unroll
    for (int j = 0; j < 4; ++j) {
      float v = rowsum[m][j];
      v += __shfl_xor(v, 1);
      v += __shfl_xor(v, 2);
      v += __shfl_xor(v, 4);
      v += __shfl_xor(v, 8);
      if (colg == 0) {
        int s = s_tile + wm * 64 + m * 16 + rowg * 4 + j;
        atomicAdd(&E[bb * kS + s], v);
      }
    }
  }
}

// ---------------- softmax over S per (b); A and new_cov ---------------------
__global__ __launch_bounds__(256) void softmax_kernel(
    const float* __restrict__ E, const float* __restrict__ coverage,
    float* __restrict__ A, float* __restrict__ newcov) {
  int b = blockIdx.x;
  int tid = threadIdx.x;
  int wid = tid >> 6, lane = tid & 63;
  __shared__ float wred[4];
  float ev[8];
  float mx = -INFINITY;
#pragma unroll
  for (int i = 0; i < 8; ++i) {
    ev[i] = E[b * kS + tid + i * 256];
    mx = fmaxf(mx, ev[i]);
  }
  for (int m = 1; m < 64; m <<= 1) mx = fmaxf(mx, __shfl_xor(mx, m));
  if (lane == 0) wred[wid] = mx;
  __syncthreads();
  mx = fmaxf(fmaxf(wred[0], wred[1]), fmaxf(wred[2], wred[3]));
  __syncthreads();
  float sum = 0.f;
#pragma unroll
  for (int i = 0; i < 8; ++i) {
    ev[i] = __expf(ev[i] - mx);
    sum += ev[i];
  }
  for (int m = 1; m < 64; m <<= 1) sum += __shfl_xor(sum, m);
  if (lane == 0) wred[wid] = sum;
  __syncthreads();
  sum = wred[0] + wred[1] + wred[2] + wred[3];
  float inv = 1.f / sum;
#pragma unroll
  for (int i = 0; i < 8; ++i) {
    int s = tid + i * 256;
    float a = ev[i] * inv;
    A[b * kS + s] = a;
    newcov[b * kS + s] = coverage[b * kS + s] + a;
  }
}

// ---------------- context C[b] = sum_s A[b,s] * h_i[b,s,:] ------------------
// grid (b, d-chunk of 1024, s-chunk of 256); atomicAdd partials into zeroed C
__global__ __launch_bounds__(256) void context_kernel(
    const float* __restrict__ h_i, const float* __restrict__ A,
    float* __restrict__ C) {
  int b = blockIdx.x;
  int d = blockIdx.y * 1024 + threadIdx.x * 4;
  int s0 = blockIdx.z * 256;
  const float* hp = h_i + ((size_t)b * kS + s0) * kD + d;
  const float* ap = A + b * kS + s0;
  float4 acc = {0.f, 0.f, 0.f, 0.f};
  for (int s = 0; s < 256; ++s) {
    float a = ap[s];  // block-uniform -> scalar load
    float4 v = *reinterpret_cast<const float4*>(hp + (size_t)s * kD);
    acc.x += a * v.x;
    acc.y += a * v.y;
    acc.z += a * v.z;
    acc.w += a * v.w;
  }
  atomicAdd(&C[b * kD + d + 0], acc.x);
  atomicAdd(&C[b * kD + d + 1], acc.y);
  atomicAdd(&C[b * kD + d + 2], acc.z);
  atomicAdd(&C[b * kD + d + 3], acc.w);
}

extern "C" void kernel_launch(void* const* d_in, const int* in_sizes, int n_in,
                              void* d_out, int out_size, void* d_ws, size_t ws_size,
                              hipStream_t stream) {
  const float* s_t      = (const float*)d_in[0];
  const float* h_i      = (const float*)d_in[1];
  const float* coverage = (const float*)d_in[2];
  const float* W_h      = (const float*)d_in[3];
  const float* b_h      = (const float*)d_in[4];
  const float* W_s      = (const float*)d_in[5];
  const float* b_s      = (const float*)d_in[6];
  const float* W_c      = (const float*)d_in[7];
  const float* v_a      = (const float*)d_in[8];
  // d_in[9] = b_a: softmax-shift-invariant and E is not an output -> unused.

  float* out = (float*)d_out;
  float* C      = out;                 // (kB, kD)
  float* A      = out + kB * kD;       // (kB, kS)
  float* newcov = A + kB * kS;         // (kB, kS)

  char* ws = (char*)d_ws;
  __bf16* Wh_bf  = (__bf16*)ws;                               // 4 MB
  float* biasBH  = (float*)(ws + (4u << 20));                 // 256 KB
  float* E       = (float*)(ws + (4u << 20) + (256u << 10));  // 512 KB

  hipMemsetAsync(E, 0, (size_t)kB * kS * sizeof(float), stream);
  hipMemsetAsync(C, 0, (size_t)kB * kD * sizeof(float), stream);

  conv_wh_kernel<<<(kH * kD / 4) / 256, 256, 0, stream>>>(W_h, Wh_bf);
  prep_bias_kernel<<<(kB * kH) / 4, 256, 0, stream>>>(s_t, W_s, b_s, b_h, biasBH);

  dim3 gg(8, kM / 128, 1);
  gemm_score_kernel<<<gg, 256, 0, stream>>>(h_i, Wh_bf, biasBH, coverage, W_c, v_a, E);

  softmax_kernel<<<kB, 256, 0, stream>>>(E, coverage, A, newcov);

  dim3 gc(kB, kD / 1024, kS / 256);
  context_kernel<<<gc, 256, 0, stream>>>(h_i, A, C);
}

// Round 2
// 1303.192 us; speedup vs baseline: 1.0395x; 1.0395x over previous
//
#include <hip/hip_runtime.h>
#include <hip/hip_bf16.h>

typedef __bf16 bf16x4_v __attribute__((ext_vector_type(4)));
typedef __bf16 bf16x8_v __attribute__((ext_vector_type(8)));
typedef float  f32x4_v  __attribute__((ext_vector_type(4)));

static constexpr int kH = 1024;
static constexpr int kD = 2048;   // 2H
static constexpr int kB = 64;
static constexpr int kS = 2048;
static constexpr int kM = kB * kS;  // 131072 rows of the big GEMM

__device__ __forceinline__ void load_lds16(const void* g, void* l) {
  __builtin_amdgcn_global_load_lds(
      (const __attribute__((address_space(1))) unsigned int*)g,
      (__attribute__((address_space(3))) unsigned int*)l, 16, 0, 0);
}

__device__ __forceinline__ float fast_tanh(float x) {
  float e = __expf(2.0f * x);
  return 1.0f - 2.0f * __builtin_amdgcn_rcpf(e + 1.0f);
}

// ---- W_h fp32 -> bf16, re-tiled for swizzled global_load_lds staging -------
// Layout: tiles [kH/8][kD/64], each tile = 8 rows x 64 cols = 512 bf16 (1024B).
// Within a tile, 16B chunk l holds LOGICAL chunk sc = l ^ (l>>3), so that a
// linear global_load_lds write produces LDS content readable with the
// byte ^= ((row&7)<<4) bank-conflict swizzle.
__global__ __launch_bounds__(256) void conv_wh_kernel(const float* __restrict__ W,
                                                      __bf16* __restrict__ out) {
  int g = blockIdx.x * 256 + threadIdx.x;   // 262144 chunks of 16B
  int tile = g >> 6, l = g & 63;
  int sc = l ^ (l >> 3);
  int h = (tile >> 5) * 8 + (sc >> 3);
  int k = (tile & 31) * 64 + (sc & 7) * 8;
  const float4* s = reinterpret_cast<const float4*>(W + (size_t)h * kD + k);
  float4 v0 = s[0], v1 = s[1];
  bf16x8_v o = {(__bf16)v0.x, (__bf16)v0.y, (__bf16)v0.z, (__bf16)v0.w,
                (__bf16)v1.x, (__bf16)v1.y, (__bf16)v1.z, (__bf16)v1.w};
  reinterpret_cast<bf16x8_v*>(out)[g] = o;
}

// ------------- biasBH[b][h] = s_t[b] . W_s[h] + b_s[h] + b_h[h] -------------
__global__ __launch_bounds__(256) void prep_bias_kernel(
    const float* __restrict__ s_t, const float* __restrict__ W_s,
    const float* __restrict__ b_s, const float* __restrict__ b_h,
    float* __restrict__ biasBH) {
  int wave = blockIdx.x * 4 + (threadIdx.x >> 6);  // 65536 outputs
  int lane = threadIdx.x & 63;
  int b = wave >> 10, h = wave & 1023;
  const float4* sp = reinterpret_cast<const float4*>(s_t + (size_t)b * kD);
  const float4* wp = reinterpret_cast<const float4*>(W_s + (size_t)h * kD);
  float acc = 0.f;
  for (int i = lane; i < kD / 4; i += 64) {
    float4 a = sp[i], w = wp[i];
    acc += a.x * w.x + a.y * w.y + a.z * w.z + a.w * w.w;
  }
  for (int m = 1; m < 64; m <<= 1) acc += __shfl_xor(acc, m);
  if (lane == 0) biasBH[wave] = acc + b_s[h] + b_h[h];
}

// ---------------- big GEMM + fused tanh/v_a epilogue -> E -------------------
// 128x128 tile, BK=64, 4 waves (2x2), 16x16x32 bf16 MFMA.
// XCD-partitioned grid: xcd = bid&7 owns M-tiles [xcd*128, xcd*128+128);
// n-chunk varies fastest within an XCD so the 8 N-blocks of an M-tile are
// co-resident on one XCD and share the A-panel through its private L2.
// Both LDS tiles are XOR-swizzled (byte ^= (row&7)<<4) for 2-way (free) reads.
__global__ void gemm_score_kernel(
    const float* __restrict__ h_i,      // (kM, kD) fp32
    const __bf16* __restrict__ Wh,      // tiled bf16 (see conv_wh_kernel)
    const float* __restrict__ biasBH,   // (kB, kH)
    const float* __restrict__ coverage, // (kB, kS)
    const float* __restrict__ Wc,       // (kH)
    const float* __restrict__ va,       // (kH)
    float* __restrict__ E) {            // (kB, kS), pre-zeroed
  const int bid = blockIdx.x;
  const int xcd = bid & 7;
  const int slot = bid >> 3;
  const int n0 = (slot & 7) * 128;
  const int m0 = (xcd * 128 + (slot >> 3)) * 128;

  const int tid = threadIdx.x;
  const int lane = tid & 63;
  const int wid = tid >> 6;        // 0..3
  const int wm = wid >> 1, wn = wid & 1;

  __shared__ __bf16 As[128 * 64];
  __shared__ __bf16 Bs[128 * 64];
  char* Asb = (char*)As;
  char* Bsb = (char*)Bs;

  f32x4_v acc[4][4];
#pragma unroll
  for (int m = 0; m < 4; ++m)
#pragma unroll
    for (int n = 0; n < 4; ++n) acc[m][n] = {0.f, 0.f, 0.f, 0.f};

  const int rA = wm * 64 + (lane & 15);
  const int rB = wn * 64 + (lane & 15);
  const int khalf = (lane >> 4) * 16;      // byte offset of k-group in 32-col half
  const int swz = (lane & 7) << 4;         // row-swizzle term (rA&7 == rB&7 == lane&7)

  for (int k0 = 0; k0 < kD; k0 += 64) {
    // ---- stage B: 4 x global_load_lds of one 8x64 pre-swizzled tile each
    {
      const int ktile = k0 >> 6;
      const __bf16* tb = Wh + ((size_t)(((n0 + wid * 32) >> 3) * 32 + ktile)) * 512
                            + (size_t)lane * 8;
#pragma unroll
      for (int p = 0; p < 4; ++p) {
        load_lds16(tb + (size_t)p * (32 * 512), Bsb + (wid * 32 + p * 8) * 128);
      }
    }
    // ---- stage A: 128x64 fp32 -> bf16, swizzled ds_write_b64
    {
      const float* Ag = h_i + (size_t)m0 * kD + k0;
#pragma unroll
      for (int j = 0; j < 8; ++j) {
        int idx = j * 256 + tid;   // 0..2047
        int row = idx >> 4;        // 0..127
        int fp = idx & 15;         // float4 position within 64-col slice
        float4 v = *reinterpret_cast<const float4*>(Ag + (size_t)row * kD + fp * 4);
        bf16x4_v o = {(__bf16)v.x, (__bf16)v.y, (__bf16)v.z, (__bf16)v.w};
        int off = row * 128 + ((fp * 8) ^ ((row & 7) << 4));
        *reinterpret_cast<bf16x4_v*>(Asb + off) = o;
      }
    }
    __syncthreads();

#pragma unroll
    for (int ks = 0; ks < 2; ++ks) {
      const int cb = (ks * 64 + khalf) ^ swz;
      bf16x8_v a[4], b[4];
#pragma unroll
      for (int m = 0; m < 4; ++m)
        a[m] = *reinterpret_cast<const bf16x8_v*>(Asb + (rA + m * 16) * 128 + cb);
#pragma unroll
      for (int n = 0; n < 4; ++n)
        b[n] = *reinterpret_cast<const bf16x8_v*>(Bsb + (rB + n * 16) * 128 + cb);
#pragma unroll
      for (int m = 0; m < 4; ++m)
#pragma unroll
        for (int n = 0; n < 4; ++n)
          acc[m][n] = __builtin_amdgcn_mfma_f32_16x16x32_bf16(a[m], b[n], acc[m][n], 0, 0, 0);
    }
    __syncthreads();
  }

  // ---- epilogue: z = acc + bias + cov*Wc; E_partial = sum_h tanh(z)*va[h]
  const int bb = m0 >> 11;            // batch (uniform per block)
  const int colg = lane & 15;
  const int rowg = lane >> 4;         // 0..3
  float bias_v[4], wc_v[4], va_v[4];
#pragma unroll
  for (int n = 0; n < 4; ++n) {
    int h = n0 + wn * 64 + n * 16 + colg;
    bias_v[n] = biasBH[bb * kH + h];
    wc_v[n] = Wc[h];
    va_v[n] = va[h];
  }
  const int s_tile = (m0 & (kS - 1));
  float rowsum[4][4];
#pragma unroll
  for (int m = 0; m < 4; ++m)
#pragma unroll
    for (int j = 0; j < 4; ++j) rowsum[m][j] = 0.f;

#pragma unroll
  for (int m = 0; m < 4; ++m) {
    int sbase = s_tile + wm * 64 + m * 16 + rowg * 4;
    float cov[4];
#pragma unroll
    for (int j = 0; j < 4; ++j) cov[j] = coverage[bb * kS + sbase + j];
#pragma unroll
    for (int n = 0; n < 4; ++n) {
#pragma unroll
      for (int j = 0; j < 4; ++j) {
        float z = acc[m][n][j] + bias_v[n] + cov[j] * wc_v[n];
        rowsum[m][j] += fast_tanh(z) * va_v[n];
      }
    }
  }
#pragma unroll
  for (int m = 0; m < 4; ++m) {
#pragma unroll
    for (int j = 0; j < 4; ++j) {
      float v = rowsum[m][j];
      v += __shfl_xor(v, 1);
      v += __shfl_xor(v, 2);
      v += __shfl_xor(v, 4);
      v += __shfl_xor(v, 8);
      if (colg == 0) {
        int s = s_tile + wm * 64 + m * 16 + rowg * 4 + j;
        atomicAdd(&E[bb * kS + s], v);
      }
    }
  }
}

// ---------------- softmax over S per (b); A and new_cov ---------------------
__global__ __launch_bounds__(256) void softmax_kernel(
    const float* __restrict__ E, const float* __restrict__ coverage,
    float* __restrict__ A, float* __restrict__ newcov) {
  int b = blockIdx.x;
  int tid = threadIdx.x;
  int wid = tid >> 6, lane = tid & 63;
  __shared__ float wred[4];
  float ev[8];
  float mx = -INFINITY;
#pragma unroll
  for (int i = 0; i < 8; ++i) {
    ev[i] = E[b * kS + tid + i * 256];
    mx = fmaxf(mx, ev[i]);
  }
  for (int m = 1; m < 64; m <<= 1) mx = fmaxf(mx, __shfl_xor(mx, m));
  if (lane == 0) wred[wid] = mx;
  __syncthreads();
  mx = fmaxf(fmaxf(wred[0], wred[1]), fmaxf(wred[2], wred[3]));
  __syncthreads();
  float sum = 0.f;
#pragma unroll
  for (int i = 0; i < 8; ++i) {
    ev[i] = __expf(ev[i] - mx);
    sum += ev[i];
  }
  for (int m = 1; m < 64; m <<= 1) sum += __shfl_xor(sum, m);
  if (lane == 0) wred[wid] = sum;
  __syncthreads();
  sum = wred[0] + wred[1] + wred[2] + wred[3];
  float inv = 1.f / sum;
#pragma unroll
  for (int i = 0; i < 8; ++i) {
    int s = tid + i * 256;
    float a = ev[i] * inv;
    A[b * kS + s] = a;
    newcov[b * kS + s] = coverage[b * kS + s] + a;
  }
}

// ---------------- context C[b] = sum_s A[b,s] * h_i[b,s,:] ------------------
__global__ __launch_bounds__(256) void context_kernel(
    const float* __restrict__ h_i, const float* __restrict__ A,
    float* __restrict__ C) {
  int b = blockIdx.x;
  int d = blockIdx.y * 1024 + threadIdx.x * 4;
  int s0 = blockIdx.z * 256;
  const float* hp = h_i + ((size_t)b * kS + s0) * kD + d;
  const float* ap = A + b * kS + s0;
  float4 acc = {0.f, 0.f, 0.f, 0.f};
  for (int s = 0; s < 256; ++s) {
    float a = ap[s];
    float4 v = *reinterpret_cast<const float4*>(hp + (size_t)s * kD);
    acc.x += a * v.x;
    acc.y += a * v.y;
    acc.z += a * v.z;
    acc.w += a * v.w;
  }
  atomicAdd(&C[b * kD + d + 0], acc.x);
  atomicAdd(&C[b * kD + d + 1], acc.y);
  atomicAdd(&C[b * kD + d + 2], acc.z);
  atomicAdd(&C[b * kD + d + 3], acc.w);
}

extern "C" void kernel_launch(void* const* d_in, const int* in_sizes, int n_in,
                              void* d_out, int out_size, void* d_ws, size_t ws_size,
                              hipStream_t stream) {
  const float* s_t      = (const float*)d_in[0];
  const float* h_i      = (const float*)d_in[1];
  const float* coverage = (const float*)d_in[2];
  const float* W_h      = (const float*)d_in[3];
  const float* b_h      = (const float*)d_in[4];
  const float* W_s      = (const float*)d_in[5];
  const float* b_s      = (const float*)d_in[6];
  const float* W_c      = (const float*)d_in[7];
  const float* v_a      = (const float*)d_in[8];
  // d_in[9] = b_a: softmax-shift-invariant and E is not an output -> unused.

  float* out = (float*)d_out;
  float* C      = out;                 // (kB, kD)
  float* A      = out + kB * kD;       // (kB, kS)
  float* newcov = A + kB * kS;         // (kB, kS)

  char* ws = (char*)d_ws;
  __bf16* Wh_bf  = (__bf16*)ws;                               // 4 MB (tiled)
  float* biasBH  = (float*)(ws + (4u << 20));                 // 256 KB
  float* E       = (float*)(ws + (4u << 20) + (256u << 10));  // 512 KB

  hipMemsetAsync(E, 0, (size_t)kB * kS * sizeof(float), stream);
  hipMemsetAsync(C, 0, (size_t)kB * kD * sizeof(float), stream);

  conv_wh_kernel<<<(kH * kD / 8) / 256, 256, 0, stream>>>(W_h, Wh_bf);
  prep_bias_kernel<<<(kB * kH) / 4, 256, 0, stream>>>(s_t, W_s, b_s, b_h, biasBH);

  gemm_score_kernel<<<8192, 256, 0, stream>>>(h_i, Wh_bf, biasBH, coverage, W_c, v_a, E);

  softmax_kernel<<<kB, 256, 0, stream>>>(E, coverage, A, newcov);

  dim3 gc(kB, kD / 1024, kS / 256);
  context_kernel<<<gc, 256, 0, stream>>>(h_i, A, C);
}

// Round 3
// 1215.078 us; speedup vs baseline: 1.1149x; 1.0725x over previous
//
#include <hip/hip_runtime.h>
#include <hip/hip_bf16.h>

typedef __bf16 bf16x4_v __attribute__((ext_vector_type(4)));
typedef __bf16 bf16x8_v __attribute__((ext_vector_type(8)));
typedef float  f32x4_v  __attribute__((ext_vector_type(4)));

static constexpr int kH = 1024;
static constexpr int kD = 2048;   // 2H
static constexpr int kB = 64;
static constexpr int kS = 2048;
static constexpr int kM = kB * kS;  // 131072 rows of the big GEMM

__device__ __forceinline__ void load_lds16(const void* g, void* l) {
  __builtin_amdgcn_global_load_lds(
      (const __attribute__((address_space(1))) unsigned int*)g,
      (__attribute__((address_space(3))) unsigned int*)l, 16, 0, 0);
}

__device__ __forceinline__ float fast_tanh(float x) {
  float e = __expf(2.0f * x);
  return 1.0f - 2.0f * __builtin_amdgcn_rcpf(e + 1.0f);
}

// ---- W_h fp32 -> bf16, re-tiled for swizzled global_load_lds staging -------
// Tiles [kH/8][kD/64], each 8x64 bf16 = 1024B; 16B chunk l holds logical
// chunk l ^ (l>>3) so linear gload_lds writes match the (row&7)<<4 read swizzle.
__global__ __launch_bounds__(256) void conv_wh_kernel(const float* __restrict__ W,
                                                      __bf16* __restrict__ out) {
  int g = blockIdx.x * 256 + threadIdx.x;   // 262144 chunks of 16B
  int tile = g >> 6, l = g & 63;
  int sc = l ^ (l >> 3);
  int h = (tile >> 5) * 8 + (sc >> 3);
  int k = (tile & 31) * 64 + (sc & 7) * 8;
  const float4* s = reinterpret_cast<const float4*>(W + (size_t)h * kD + k);
  float4 v0 = s[0], v1 = s[1];
  bf16x8_v o = {(__bf16)v0.x, (__bf16)v0.y, (__bf16)v0.z, (__bf16)v0.w,
                (__bf16)v1.x, (__bf16)v1.y, (__bf16)v1.z, (__bf16)v1.w};
  reinterpret_cast<bf16x8_v*>(out)[g] = o;
}

// ------------- biasBH[b][h] = s_t[b] . W_s[h] + b_s[h] + b_h[h] -------------
__global__ __launch_bounds__(256) void prep_bias_kernel(
    const float* __restrict__ s_t, const float* __restrict__ W_s,
    const float* __restrict__ b_s, const float* __restrict__ b_h,
    float* __restrict__ biasBH) {
  int wave = blockIdx.x * 4 + (threadIdx.x >> 6);  // 65536 outputs
  int lane = threadIdx.x & 63;
  int b = wave >> 10, h = wave & 1023;
  const float4* sp = reinterpret_cast<const float4*>(s_t + (size_t)b * kD);
  const float4* wp = reinterpret_cast<const float4*>(W_s + (size_t)h * kD);
  float acc = 0.f;
  for (int i = lane; i < kD / 4; i += 64) {
    float4 a = sp[i], w = wp[i];
    acc += a.x * w.x + a.y * w.y + a.z * w.z + a.w * w.w;
  }
  for (int m = 1; m < 64; m <<= 1) acc += __shfl_xor(acc, m);
  if (lane == 0) biasBH[wave] = acc + b_s[h] + b_h[h];
}

// ---------------- big GEMM + fused tanh/v_a epilogue -> E -------------------
// 128x128 tile, BK=64, 4 waves (2x2), double-buffered LDS (64 KB), T14
// async-STAGE split: issue next-tile A(reg)/B(gload_lds) BEFORE the MFMA
// phase, convert+ds_write A AFTER it. One barrier per K-step.
__global__ __launch_bounds__(256) void gemm_score_kernel(
    const float* __restrict__ h_i,      // (kM, kD) fp32
    const __bf16* __restrict__ Wh,      // tiled bf16 (see conv_wh_kernel)
    const float* __restrict__ biasBH,   // (kB, kH)
    const float* __restrict__ coverage, // (kB, kS)
    const float* __restrict__ Wc,       // (kH)
    const float* __restrict__ va,       // (kH)
    float* __restrict__ E) {            // (kB, kS), pre-zeroed
  const int bid = blockIdx.x;
  const int xcd = bid & 7;
  const int slot = bid >> 3;
  const int n0 = (slot & 7) * 128;
  const int m0 = (xcd * 128 + (slot >> 3)) * 128;

  const int tid = threadIdx.x;
  const int lane = tid & 63;
  const int wid = tid >> 6;        // 0..3
  const int wm = wid >> 1, wn = wid & 1;

  __shared__ __bf16 As[2][128 * 64];
  __shared__ __bf16 Bs[2][128 * 64];
  char* Asb = (char*)As;
  char* Bsb = (char*)Bs;

  f32x4_v acc[4][4];
#pragma unroll
  for (int m = 0; m < 4; ++m)
#pragma unroll
    for (int n = 0; n < 4; ++n) acc[m][n] = {0.f, 0.f, 0.f, 0.f};

  const int rA = wm * 64 + (lane & 15);
  const int rB = wn * 64 + (lane & 15);
  const int khalf = (lane >> 4) * 16;      // byte offset of k-group in 32-col half
  const int swz = (lane & 7) << 4;         // row-swizzle term

  // A-staging geometry (per thread: 8 float4 = one 128x64 fp32 tile / block)
  const int arow = tid >> 4;               // base row pattern: idx=j*256+tid
  const int afp = tid & 15;
  const float* Ag0 = h_i + (size_t)m0 * kD;
  // B-staging base (wave-wide): tile ptr for wave's 32 rows
  const __bf16* Btb = Wh + ((size_t)(((n0 + wid * 32) >> 3) * 32)) * 512 + (size_t)lane * 8;

  float4 av[8];

  // ---- prologue: stage K-step 0 into buf 0
  {
#pragma unroll
    for (int p = 0; p < 4; ++p)
      load_lds16(Btb + (size_t)p * (32 * 512), Bsb + (wid * 32 + p * 8) * 128);
#pragma unroll
    for (int j = 0; j < 8; ++j) {
      int row = (j * 256 + tid) >> 4;
      av[j] = *reinterpret_cast<const float4*>(Ag0 + (size_t)row * kD + afp * 4);
    }
#pragma unroll
    for (int j = 0; j < 8; ++j) {
      int row = (j * 256 + tid) >> 4;
      bf16x4_v o = {(__bf16)av[j].x, (__bf16)av[j].y, (__bf16)av[j].z, (__bf16)av[j].w};
      *reinterpret_cast<bf16x4_v*>(Asb + row * 128 + ((afp * 8) ^ ((row & 7) << 4))) = o;
    }
  }
  __syncthreads();

  for (int t = 0; t < 32; ++t) {
    const int cur = t & 1;
    char* Ab = Asb + cur * 16384;
    char* Bb = Bsb + cur * 16384;
    char* An = Asb + (cur ^ 1) * 16384;
    char* Bn = Bsb + (cur ^ 1) * 16384;

    // ---- issue next-tile staging (loads in flight across the MFMA phase)
    if (t < 31) {
#pragma unroll
      for (int p = 0; p < 4; ++p)
        load_lds16(Btb + (size_t)((t + 1) * 512 + p * (32 * 512)), Bn + (wid * 32 + p * 8) * 128);
      const float* Ag = Ag0 + (t + 1) * 64;
#pragma unroll
      for (int j = 0; j < 8; ++j) {
        int row = (j * 256 + tid) >> 4;
        av[j] = *reinterpret_cast<const float4*>(Ag + (size_t)row * kD + afp * 4);
      }
    }

    // ---- MFMA phase on buf cur
#pragma unroll
    for (int ks = 0; ks < 2; ++ks) {
      const int cb = (ks * 64 + khalf) ^ swz;
      bf16x8_v a[4], b[4];
#pragma unroll
      for (int m = 0; m < 4; ++m)
        a[m] = *reinterpret_cast<const bf16x8_v*>(Ab + (rA + m * 16) * 128 + cb);
#pragma unroll
      for (int n = 0; n < 4; ++n)
        b[n] = *reinterpret_cast<const bf16x8_v*>(Bb + (rB + n * 16) * 128 + cb);
#pragma unroll
      for (int m = 0; m < 4; ++m)
#pragma unroll
        for (int n = 0; n < 4; ++n)
          acc[m][n] = __builtin_amdgcn_mfma_f32_16x16x32_bf16(a[m], b[n], acc[m][n], 0, 0, 0);
    }

    // ---- write converted A into next buf (loads have landed by now)
    if (t < 31) {
#pragma unroll
      for (int j = 0; j < 8; ++j) {
        int row = (j * 256 + tid) >> 4;
        bf16x4_v o = {(__bf16)av[j].x, (__bf16)av[j].y, (__bf16)av[j].z, (__bf16)av[j].w};
        *reinterpret_cast<bf16x4_v*>(An + row * 128 + ((afp * 8) ^ ((row & 7) << 4))) = o;
      }
    }
    __syncthreads();
  }

  // ---- epilogue: z = acc + bias + cov*Wc; E_partial = sum_h tanh(z)*va[h]
  const int bb = m0 >> 11;            // batch (uniform per block)
  const int colg = lane & 15;
  const int rowg = lane >> 4;         // 0..3
  float bias_v[4], wc_v[4], va_v[4];
#pragma unroll
  for (int n = 0; n < 4; ++n) {
    int h = n0 + wn * 64 + n * 16 + colg;
    bias_v[n] = biasBH[bb * kH + h];
    wc_v[n] = Wc[h];
    va_v[n] = va[h];
  }
  const int s_tile = (m0 & (kS - 1));
  float rowsum[4][4];
#pragma unroll
  for (int m = 0; m < 4; ++m)
#pragma unroll
    for (int j = 0; j < 4; ++j) rowsum[m][j] = 0.f;

#pragma unroll
  for (int m = 0; m < 4; ++m) {
    int sbase = s_tile + wm * 64 + m * 16 + rowg * 4;
    float cov[4];
#pragma unroll
    for (int j = 0; j < 4; ++j) cov[j] = coverage[bb * kS + sbase + j];
#pragma unroll
    for (int n = 0; n < 4; ++n) {
#pragma unroll
      for (int j = 0; j < 4; ++j) {
        float z = acc[m][n][j] + bias_v[n] + cov[j] * wc_v[n];
        rowsum[m][j] += fast_tanh(z) * va_v[n];
      }
    }
  }
#pragma unroll
  for (int m = 0; m < 4; ++m) {
#pragma unroll
    for (int j = 0; j < 4; ++j) {
      float v = rowsum[m][j];
      v += __shfl_xor(v, 1);
      v += __shfl_xor(v, 2);
      v += __shfl_xor(v, 4);
      v += __shfl_xor(v, 8);
      if (colg == 0) {
        int s = s_tile + wm * 64 + m * 16 + rowg * 4 + j;
        atomicAdd(&E[bb * kS + s], v);
      }
    }
  }
}

// ---------------- softmax over S per (b); A and new_cov ---------------------
__global__ __launch_bounds__(256) void softmax_kernel(
    const float* __restrict__ E, const float* __restrict__ coverage,
    float* __restrict__ A, float* __restrict__ newcov) {
  int b = blockIdx.x;
  int tid = threadIdx.x;
  int wid = tid >> 6, lane = tid & 63;
  __shared__ float wred[4];
  float ev[8];
  float mx = -INFINITY;
#pragma unroll
  for (int i = 0; i < 8; ++i) {
    ev[i] = E[b * kS + tid + i * 256];
    mx = fmaxf(mx, ev[i]);
  }
  for (int m = 1; m < 64; m <<= 1) mx = fmaxf(mx, __shfl_xor(mx, m));
  if (lane == 0) wred[wid] = mx;
  __syncthreads();
  mx = fmaxf(fmaxf(wred[0], wred[1]), fmaxf(wred[2], wred[3]));
  __syncthreads();
  float sum = 0.f;
#pragma unroll
  for (int i = 0; i < 8; ++i) {
    ev[i] = __expf(ev[i] - mx);
    sum += ev[i];
  }
  for (int m = 1; m < 64; m <<= 1) sum += __shfl_xor(sum, m);
  if (lane == 0) wred[wid] = sum;
  __syncthreads();
  sum = wred[0] + wred[1] + wred[2] + wred[3];
  float inv = 1.f / sum;
#pragma unroll
  for (int i = 0; i < 8; ++i) {
    int s = tid + i * 256;
    float a = ev[i] * inv;
    A[b * kS + s] = a;
    newcov[b * kS + s] = coverage[b * kS + s] + a;
  }
}

// ---------------- context C[b] = sum_s A[b,s] * h_i[b,s,:] ------------------
__global__ __launch_bounds__(256) void context_kernel(
    const float* __restrict__ h_i, const float* __restrict__ A,
    float* __restrict__ C) {
  int b = blockIdx.x;
  int d = blockIdx.y * 1024 + threadIdx.x * 4;
  int s0 = blockIdx.z * 256;
  const float* hp = h_i + ((size_t)b * kS + s0) * kD + d;
  const float* ap = A + b * kS + s0;
  float4 acc = {0.f, 0.f, 0.f, 0.f};
  for (int s = 0; s < 256; ++s) {
    float a = ap[s];
    float4 v = *reinterpret_cast<const float4*>(hp + (size_t)s * kD);
    acc.x += a * v.x;
    acc.y += a * v.y;
    acc.z += a * v.z;
    acc.w += a * v.w;
  }
  atomicAdd(&C[b * kD + d + 0], acc.x);
  atomicAdd(&C[b * kD + d + 1], acc.y);
  atomicAdd(&C[b * kD + d + 2], acc.z);
  atomicAdd(&C[b * kD + d + 3], acc.w);
}

extern "C" void kernel_launch(void* const* d_in, const int* in_sizes, int n_in,
                              void* d_out, int out_size, void* d_ws, size_t ws_size,
                              hipStream_t stream) {
  const float* s_t      = (const float*)d_in[0];
  const float* h_i      = (const float*)d_in[1];
  const float* coverage = (const float*)d_in[2];
  const float* W_h      = (const float*)d_in[3];
  const float* b_h      = (const float*)d_in[4];
  const float* W_s      = (const float*)d_in[5];
  const float* b_s      = (const float*)d_in[6];
  const float* W_c      = (const float*)d_in[7];
  const float* v_a      = (const float*)d_in[8];
  // d_in[9] = b_a: softmax-shift-invariant and E is not an output -> unused.

  float* out = (float*)d_out;
  float* C      = out;                 // (kB, kD)
  float* A      = out + kB * kD;       // (kB, kS)
  float* newcov = A + kB * kS;         // (kB, kS)

  char* ws = (char*)d_ws;
  __bf16* Wh_bf  = (__bf16*)ws;                               // 4 MB (tiled)
  float* biasBH  = (float*)(ws + (4u << 20));                 // 256 KB
  float* E       = (float*)(ws + (4u << 20) + (256u << 10));  // 512 KB

  hipMemsetAsync(E, 0, (size_t)kB * kS * sizeof(float), stream);
  hipMemsetAsync(C, 0, (size_t)kB * kD * sizeof(float), stream);

  conv_wh_kernel<<<(kH * kD / 8) / 256, 256, 0, stream>>>(W_h, Wh_bf);
  prep_bias_kernel<<<(kB * kH) / 4, 256, 0, stream>>>(s_t, W_s, b_s, b_h, biasBH);

  gemm_score_kernel<<<8192, 256, 0, stream>>>(h_i, Wh_bf, biasBH, coverage, W_c, v_a, E);

  softmax_kernel<<<kB, 256, 0, stream>>>(E, coverage, A, newcov);

  dim3 gc(kB, kD / 1024, kS / 256);
  context_kernel<<<gc, 256, 0, stream>>>(h_i, A, C);
}

// Round 5
// 1103.243 us; speedup vs baseline: 1.2279x; 1.1014x over previous
//
#include <hip/hip_runtime.h>
#include <hip/hip_bf16.h>

typedef __bf16 bf16x4_v __attribute__((ext_vector_type(4)));
typedef __bf16 bf16x8_v __attribute__((ext_vector_type(8)));
typedef float  f32x4_v  __attribute__((ext_vector_type(4)));

static constexpr int kH = 1024;
static constexpr int kD = 2048;   // 2H
static constexpr int kB = 64;
static constexpr int kS = 2048;
static constexpr int kM = kB * kS;  // 131072 rows of the big GEMM

__device__ __forceinline__ void load_lds16(const void* g, void* l) {
  __builtin_amdgcn_global_load_lds(
      (const __attribute__((address_space(1))) unsigned int*)g,
      (__attribute__((address_space(3))) unsigned int*)l, 16, 0, 0);
}

__device__ __forceinline__ float fast_tanh(float x) {
  float e = __expf(2.0f * x);
  return 1.0f - 2.0f * __builtin_amdgcn_rcpf(e + 1.0f);
}

// ---- W_h fp32 -> bf16, re-tiled for swizzled global_load_lds staging -------
// Tiles [kH/8][kD/64], each 8x64 bf16 = 1024B; 16B chunk l holds logical
// chunk l ^ (l>>3) so linear gload_lds writes match the (row&7)<<4 read swizzle.
__global__ __launch_bounds__(256) void conv_wh_kernel(const float* __restrict__ W,
                                                      __bf16* __restrict__ out) {
  int g = blockIdx.x * 256 + threadIdx.x;   // 262144 chunks of 16B
  int tile = g >> 6, l = g & 63;
  int sc = l ^ (l >> 3);
  int h = (tile >> 5) * 8 + (sc >> 3);
  int k = (tile & 31) * 64 + (sc & 7) * 8;
  const float4* s = reinterpret_cast<const float4*>(W + (size_t)h * kD + k);
  float4 v0 = s[0], v1 = s[1];
  bf16x8_v o = {(__bf16)v0.x, (__bf16)v0.y, (__bf16)v0.z, (__bf16)v0.w,
                (__bf16)v1.x, (__bf16)v1.y, (__bf16)v1.z, (__bf16)v1.w};
  reinterpret_cast<bf16x8_v*>(out)[g] = o;
}

// ------------- biasBH[b][h] = s_t[b] . W_s[h] + b_s[h] + b_h[h] -------------
__global__ __launch_bounds__(256) void prep_bias_kernel(
    const float* __restrict__ s_t, const float* __restrict__ W_s,
    const float* __restrict__ b_s, const float* __restrict__ b_h,
    float* __restrict__ biasBH) {
  int wave = blockIdx.x * 4 + (threadIdx.x >> 6);  // 65536 outputs
  int lane = threadIdx.x & 63;
  int b = wave >> 10, h = wave & 1023;
  const float4* sp = reinterpret_cast<const float4*>(s_t + (size_t)b * kD);
  const float4* wp = reinterpret_cast<const float4*>(W_s + (size_t)h * kD);
  float acc = 0.f;
  for (int i = lane; i < kD / 4; i += 64) {
    float4 a = sp[i], w = wp[i];
    acc += a.x * w.x + a.y * w.y + a.z * w.z + a.w * w.w;
  }
  for (int m = 1; m < 64; m <<= 1) acc += __shfl_xor(acc, m);
  if (lane == 0) biasBH[wave] = acc + b_s[h] + b_h[h];
}

// ---------------- big GEMM + fused tanh/v_a epilogue -> E -------------------
// 128x128 tile, BK=64, 4 waves (2x2). 2-step-deep software pipeline:
//  - A: global fp32 loads issued 2 steps ahead into alternating reg sets
//    (av0/av1), cvt+swizzled ds_write one step ahead (2 LDS bufs).
//  - B: global_load_lds issued 2 steps ahead (3 LDS bufs).
//  - raw s_barrier + lgkmcnt(0) only: vmcnt is NEVER drained to 0 in the
//    loop; B-completion is implied by the av-use vmcnt waits because
//    B-issues always precede A-issues (sched_barrier-pinned).
__global__ __launch_bounds__(256, 2) void gemm_score_kernel(
    const float* __restrict__ h_i,      // (kM, kD) fp32
    const __bf16* __restrict__ Wh,      // tiled bf16 (see conv_wh_kernel)
    const float* __restrict__ biasBH,   // (kB, kH)
    const float* __restrict__ coverage, // (kB, kS)
    const float* __restrict__ Wc,       // (kH)
    const float* __restrict__ va,       // (kH)
    float* __restrict__ E) {            // (kB, kS), pre-zeroed
  const int bid = blockIdx.x;
  const int xcd = bid & 7;
  const int slot = bid >> 3;
  const int n0 = (slot & 7) * 128;
  const int m0 = (xcd * 128 + (slot >> 3)) * 128;

  const int tid = threadIdx.x;
  const int lane = tid & 63;
  const int wid = tid >> 6;        // 0..3
  const int wm = wid >> 1, wn = wid & 1;

  __shared__ __bf16 As[2][128 * 64];   // 32 KB
  __shared__ __bf16 Bs[3][128 * 64];   // 48 KB
  char* Asb = (char*)As;
  char* Bsb = (char*)Bs;

  f32x4_v acc[4][4];
#pragma unroll
  for (int m = 0; m < 4; ++m)
#pragma unroll
    for (int n = 0; n < 4; ++n) acc[m][n] = {0.f, 0.f, 0.f, 0.f};

  const int rA = wm * 64 + (lane & 15);
  const int rB = wn * 64 + (lane & 15);
  const int khalf = (lane >> 4) * 16;      // byte offset of k-group in 32-col half
  const int swz = (lane & 7) << 4;         // row-swizzle term

  const int afp = tid & 15;
  const float* Ag0 = h_i + (size_t)m0 * kD;
  const __bf16* Btb = Wh + ((size_t)(((n0 + wid * 32) >> 3) * 32)) * 512 + (size_t)lane * 8;

  float4 av0[8], av1[8];

  // ---- prologue: B(0)->buf0, B(1)->buf1; A(0)->av0, A(1)->av1; cvt av0->Abuf0
  {
#pragma unroll
    for (int p = 0; p < 4; ++p)
      load_lds16(Btb + (size_t)p * (32 * 512), Bsb + (wid * 32 + p * 8) * 128);
#pragma unroll
    for (int p = 0; p < 4; ++p)
      load_lds16(Btb + 512 + (size_t)p * (32 * 512), Bsb + 16384 + (wid * 32 + p * 8) * 128);
    __builtin_amdgcn_sched_barrier(0);
#pragma unroll
    for (int j = 0; j < 8; ++j) {
      int row = (j * 256 + tid) >> 4;
      av0[j] = *reinterpret_cast<const float4*>(Ag0 + (size_t)row * kD + afp * 4);
    }
#pragma unroll
    for (int j = 0; j < 8; ++j) {
      int row = (j * 256 + tid) >> 4;
      av1[j] = *reinterpret_cast<const float4*>(Ag0 + 64 + (size_t)row * kD + afp * 4);
    }
#pragma unroll
    for (int j = 0; j < 8; ++j) {
      int row = (j * 256 + tid) >> 4;
      bf16x4_v o = {(__bf16)av0[j].x, (__bf16)av0[j].y, (__bf16)av0[j].z, (__bf16)av0[j].w};
      *reinterpret_cast<bf16x4_v*>(Asb + row * 128 + ((afp * 8) ^ ((row & 7) << 4))) = o;
    }
    asm volatile("s_waitcnt lgkmcnt(0)" ::: "memory");
    __builtin_amdgcn_s_barrier();
    asm volatile("" ::: "memory");
  }

#define GEMM_STEP(AVI, AVC, S)                                                  \
  do {                                                                          \
    if ((S) + 2 < 32) {                                                         \
      char* Bn = Bsb + (((S) + 2) % 3) * 16384;                                 \
      const __bf16* tb2 = Btb + (size_t)((S) + 2) * 512;                        \
      _Pragma("unroll")                                                         \
      for (int p = 0; p < 4; ++p)                                               \
        load_lds16(tb2 + (size_t)p * (32 * 512), Bn + (wid * 32 + p * 8) * 128);\
    }                                                                           \
    __builtin_amdgcn_sched_barrier(0);                                          \
    if ((S) + 2 < 32) {                                                         \
      const float* Ag = Ag0 + (size_t)((S) + 2) * 64;                           \
      _Pragma("unroll")                                                         \
      for (int j = 0; j < 8; ++j) {                                             \
        int row = (j * 256 + tid) >> 4;                                         \
        AVI[j] = *reinterpret_cast<const float4*>(Ag + (size_t)row * kD + afp * 4); \
      }                                                                         \
    }                                                                           \
    __builtin_amdgcn_sched_barrier(0);                                          \
    {                                                                           \
      char* Ab = Asb + ((S) & 1) * 16384;                                       \
      char* Bb = Bsb + ((S) % 3) * 16384;                                       \
      __builtin_amdgcn_s_setprio(1);                                            \
      _Pragma("unroll")                                                         \
      for (int ks = 0; ks < 2; ++ks) {                                          \
        const int cb = (ks * 64 + khalf) ^ swz;                                 \
        bf16x8_v a[4], b[4];                                                    \
        _Pragma("unroll")                                                       \
        for (int m = 0; m < 4; ++m)                                             \
          a[m] = *reinterpret_cast<const bf16x8_v*>(Ab + (rA + m * 16) * 128 + cb); \
        _Pragma("unroll")                                                       \
        for (int n = 0; n < 4; ++n)                                             \
          b[n] = *reinterpret_cast<const bf16x8_v*>(Bb + (rB + n * 16) * 128 + cb); \
        _Pragma("unroll")                                                       \
        for (int m = 0; m < 4; ++m)                                             \
          _Pragma("unroll")                                                     \
          for (int n = 0; n < 4; ++n)                                           \
            acc[m][n] = __builtin_amdgcn_mfma_f32_16x16x32_bf16(a[m], b[n], acc[m][n], 0, 0, 0); \
      }                                                                         \
      __builtin_amdgcn_s_setprio(0);                                            \
    }                                                                           \
    if ((S) + 1 < 32) {                                                         \
      char* An = Asb + (((S) + 1) & 1) * 16384;                                 \
      _Pragma("unroll")                                                         \
      for (int j = 0; j < 8; ++j) {                                             \
        int row = (j * 256 + tid) >> 4;                                         \
        bf16x4_v o = {(__bf16)AVC[j].x, (__bf16)AVC[j].y, (__bf16)AVC[j].z, (__bf16)AVC[j].w}; \
        *reinterpret_cast<bf16x4_v*>(An + row * 128 + ((afp * 8) ^ ((row & 7) << 4))) = o; \
      }                                                                         \
    }                                                                           \
    asm volatile("s_waitcnt lgkmcnt(0)" ::: "memory");                          \
    __builtin_amdgcn_s_barrier();                                               \
    asm volatile("" ::: "memory");                                              \
  } while (0)

  for (int s = 0; s < 32; s += 2) {
    GEMM_STEP(av0, av1, s);
    GEMM_STEP(av1, av0, s + 1);
  }
#undef GEMM_STEP

  // ---- epilogue: z = acc + bias + cov*Wc; E_partial = sum_h tanh(z)*va[h]
  const int bb = m0 >> 11;            // batch (uniform per block)
  const int colg = lane & 15;
  const int rowg = lane >> 4;         // 0..3
  float bias_v[4], wc_v[4], va_v[4];
#pragma unroll
  for (int n = 0; n < 4; ++n) {
    int h = n0 + wn * 64 + n * 16 + colg;
    bias_v[n] = biasBH[bb * kH + h];
    wc_v[n] = Wc[h];
    va_v[n] = va[h];
  }
  const int s_tile = (m0 & (kS - 1));
  float rowsum[4][4];
#pragma unroll
  for (int m = 0; m < 4; ++m)
#pragma unroll
    for (int j = 0; j < 4; ++j) rowsum[m][j] = 0.f;

#pragma unroll
  for (int m = 0; m < 4; ++m) {
    int sbase = s_tile + wm * 64 + m * 16 + rowg * 4;
    float cov[4];
#pragma unroll
    for (int j = 0; j < 4; ++j) cov[j] = coverage[bb * kS + sbase + j];
#pragma unroll
    for (int n = 0; n < 4; ++n) {
#pragma unroll
      for (int j = 0; j < 4; ++j) {
        float z = acc[m][n][j] + bias_v[n] + cov[j] * wc_v[n];
        rowsum[m][j] += fast_tanh(z) * va_v[n];
      }
    }
  }
#pragma unroll
  for (int m = 0; m < 4; ++m) {
#pragma unroll
    for (int j = 0; j < 4; ++j) {
      float v = rowsum[m][j];
      v += __shfl_xor(v, 1);
      v += __shfl_xor(v, 2);
      v += __shfl_xor(v, 4);
      v += __shfl_xor(v, 8);
      if (colg == 0) {
        int s = s_tile + wm * 64 + m * 16 + rowg * 4 + j;
        atomicAdd(&E[bb * kS + s], v);
      }
    }
  }
}

// ---------------- softmax over S per (b); A and new_cov ---------------------
__global__ __launch_bounds__(256) void softmax_kernel(
    const float* __restrict__ E, const float* __restrict__ coverage,
    float* __restrict__ A, float* __restrict__ newcov) {
  int b = blockIdx.x;
  int tid = threadIdx.x;
  int wid = tid >> 6, lane = tid & 63;
  __shared__ float wred[4];
  float ev[8];
  float mx = -INFINITY;
#pragma unroll
  for (int i = 0; i < 8; ++i) {
    ev[i] = E[b * kS + tid + i * 256];
    mx = fmaxf(mx, ev[i]);
  }
  for (int m = 1; m < 64; m <<= 1) mx = fmaxf(mx, __shfl_xor(mx, m));
  if (lane == 0) wred[wid] = mx;
  __syncthreads();
  mx = fmaxf(fmaxf(wred[0], wred[1]), fmaxf(wred[2], wred[3]));
  __syncthreads();
  float sum = 0.f;
#pragma unroll
  for (int i = 0; i < 8; ++i) {
    ev[i] = __expf(ev[i] - mx);
    sum += ev[i];
  }
  for (int m = 1; m < 64; m <<= 1) sum += __shfl_xor(sum, m);
  if (lane == 0) wred[wid] = sum;
  __syncthreads();
  sum = wred[0] + wred[1] + wred[2] + wred[3];
  float inv = 1.f / sum;
#pragma unroll
  for (int i = 0; i < 8; ++i) {
    int s = tid + i * 256;
    float a = ev[i] * inv;
    A[b * kS + s] = a;
    newcov[b * kS + s] = coverage[b * kS + s] + a;
  }
}

// ---------------- context C[b] = sum_s A[b,s] * h_i[b,s,:] ------------------
__global__ __launch_bounds__(256) void context_kernel(
    const float* __restrict__ h_i, const float* __restrict__ A,
    float* __restrict__ C) {
  int b = blockIdx.x;
  int d = blockIdx.y * 1024 + threadIdx.x * 4;
  int s0 = blockIdx.z * 256;
  const float* hp = h_i + ((size_t)b * kS + s0) * kD + d;
  const float* ap = A + b * kS + s0;
  float4 acc = {0.f, 0.f, 0.f, 0.f};
  for (int s = 0; s < 256; ++s) {
    float a = ap[s];
    float4 v = *reinterpret_cast<const float4*>(hp + (size_t)s * kD);
    acc.x += a * v.x;
    acc.y += a * v.y;
    acc.z += a * v.z;
    acc.w += a * v.w;
  }
  atomicAdd(&C[b * kD + d + 0], acc.x);
  atomicAdd(&C[b * kD + d + 1], acc.y);
  atomicAdd(&C[b * kD + d + 2], acc.z);
  atomicAdd(&C[b * kD + d + 3], acc.w);
}

extern "C" void kernel_launch(void* const* d_in, const int* in_sizes, int n_in,
                              void* d_out, int out_size, void* d_ws, size_t ws_size,
                              hipStream_t stream) {
  const float* s_t      = (const float*)d_in[0];
  const float* h_i      = (const float*)d_in[1];
  const float* coverage = (const float*)d_in[2];
  const float* W_h      = (const float*)d_in[3];
  const float* b_h      = (const float*)d_in[4];
  const float* W_s      = (const float*)d_in[5];
  const float* b_s      = (const float*)d_in[6];
  const float* W_c      = (const float*)d_in[7];
  const float* v_a      = (const float*)d_in[8];
  // d_in[9] = b_a: softmax-shift-invariant and E is not an output -> unused.

  float* out = (float*)d_out;
  float* C      = out;                 // (kB, kD)
  float* A      = out + kB * kD;       // (kB, kS)
  float* newcov = A + kB * kS;         // (kB, kS)

  char* ws = (char*)d_ws;
  __bf16* Wh_bf  = (__bf16*)ws;                               // 4 MB (tiled)
  float* biasBH  = (float*)(ws + (4u << 20));                 // 256 KB
  float* E       = (float*)(ws + (4u << 20) + (256u << 10));  // 512 KB

  hipMemsetAsync(E, 0, (size_t)kB * kS * sizeof(float), stream);
  hipMemsetAsync(C, 0, (size_t)kB * kD * sizeof(float), stream);

  conv_wh_kernel<<<(kH * kD / 8) / 256, 256, 0, stream>>>(W_h, Wh_bf);
  prep_bias_kernel<<<(kB * kH) / 4, 256, 0, stream>>>(s_t, W_s, b_s, b_h, biasBH);

  gemm_score_kernel<<<8192, 256, 0, stream>>>(h_i, Wh_bf, biasBH, coverage, W_c, v_a, E);

  softmax_kernel<<<kB, 256, 0, stream>>>(E, coverage, A, newcov);

  dim3 gc(kB, kD / 1024, kS / 256);
  context_kernel<<<gc, 256, 0, stream>>>(h_i, A, C);
}